// Round 1
// baseline (684.907 us; speedup 1.0000x reference)
//
#include <hip/hip_runtime.h>
#include <limits.h>
#include <math.h>

// ---------------------------------------------------------------------------
// Generic (val, idx) comparator with stable lowest-index tie-break, matching
// jax.lax.top_k semantics (for smallest-k the reference negates, which also
// yields lowest-index-wins on ties of the original values).
// ---------------------------------------------------------------------------
template<bool LG>
__device__ __forceinline__ bool better(float v, int i, float w, int j) {
    return LG ? (v > w || (v == w && i < j))
              : (v < w || (v == w && i < j));
}

// Insert (x, xi) into a best-first sorted 4-list. Static indexing only.
template<bool LG>
__device__ __forceinline__ void ins4(float x, int xi,
    float& s0, float& s1, float& s2, float& s3,
    int& j0, int& j1, int& j2, int& j3)
{
    if (!better<LG>(x, xi, s3, j3)) return;
    if (better<LG>(x, xi, s2, j2)) {
        s3 = s2; j3 = j2;
        if (better<LG>(x, xi, s1, j1)) {
            s2 = s1; j2 = j1;
            if (better<LG>(x, xi, s0, j0)) { s1 = s0; j1 = j0; s0 = x; j0 = xi; }
            else                           { s1 = x;  j1 = xi; }
        } else { s2 = x; j2 = xi; }
    } else { s3 = x; j3 = xi; }
}

// Insert into best-first sorted 3-list.
template<bool LG>
__device__ __forceinline__ void ins3(float x, int xi,
    float& s0, float& s1, float& s2,
    int& j0, int& j1, int& j2)
{
    if (!better<LG>(x, xi, s2, j2)) return;
    if (better<LG>(x, xi, s1, j1)) {
        s2 = s1; j2 = j1;
        if (better<LG>(x, xi, s0, j0)) { s1 = s0; j1 = j0; s0 = x; j0 = xi; }
        else                           { s1 = x;  j1 = xi; }
    } else { s2 = x; j2 = xi; }
}

// Compare-exchange: ensure x is the better element.
template<bool LG>
__device__ __forceinline__ void ce(float& x, int& xi, float& y, int& yi) {
    if (!better<LG>(x, xi, y, yi)) {
        float tv = x; x = y; y = tv;
        int   ti = xi; xi = yi; yi = ti;
    }
}

// Branch-free-ish merge of two best-first sorted 4-lists -> best 4 (into A).
// Bitonic: L[i] = better(A[i], B[3-i]); then CE(0,2) CE(1,3) CE(0,1) CE(2,3).
template<bool LG>
__device__ __forceinline__ void merge4(
    float& a0, float& a1, float& a2, float& a3,
    int& i0, int& i1, int& i2, int& i3,
    float b0, float b1, float b2, float b3,
    int j0, int j1, int j2, int j3)
{
    bool c;
    float l0, l1, l2, l3; int m0, m1, m2, m3;
    c = better<LG>(a0, i0, b3, j3); l0 = c ? a0 : b3; m0 = c ? i0 : j3;
    c = better<LG>(a1, i1, b2, j2); l1 = c ? a1 : b2; m1 = c ? i1 : j2;
    c = better<LG>(a2, i2, b1, j1); l2 = c ? a2 : b1; m2 = c ? i2 : j1;
    c = better<LG>(a3, i3, b0, j0); l3 = c ? a3 : b0; m3 = c ? i3 : j0;
    ce<LG>(l0, m0, l2, m2); ce<LG>(l1, m1, l3, m3);
    ce<LG>(l0, m0, l1, m1); ce<LG>(l2, m2, l3, m3);
    a0 = l0; a1 = l1; a2 = l2; a3 = l3;
    i0 = m0; i1 = m1; i2 = m2; i3 = m3;
}

// ---------------------------------------------------------------------------
// Kernel 0: v_0 (4096, 32000), top-2 largest along dim 1. One wave per row.
// ---------------------------------------------------------------------------
__global__ __launch_bounds__(256) void topk0_kernel(
    const float* __restrict__ x, float* __restrict__ outv, float* __restrict__ outi)
{
    const int wave = threadIdx.x >> 6;
    const int lane = threadIdx.x & 63;
    const int row  = blockIdx.x * 4 + wave;
    const float4* xr = (const float4*)(x + (size_t)row * 32000);

    float a0 = -INFINITY, a1 = -INFINITY;
    int   i0 = INT_MAX,   i1 = INT_MAX;

    for (int v = lane; v < 8000; v += 64) {
        float4 t = xr[v];
        int base = v * 4;
#define UPD2(val, ii) { float xv = (val); int xi = (ii);                         \
        if (better<true>(xv, xi, a1, i1)) {                                      \
            if (better<true>(xv, xi, a0, i0)) { a1 = a0; i1 = i0; a0 = xv; i0 = xi; } \
            else                              { a1 = xv; i1 = xi; } } }
        UPD2(t.x, base); UPD2(t.y, base + 1); UPD2(t.z, base + 2); UPD2(t.w, base + 3);
#undef UPD2
    }

    // butterfly merge of sorted 2-lists across the wave
    for (int m = 1; m < 64; m <<= 1) {
        float b0 = __shfl_xor(a0, m); int j0 = __shfl_xor(i0, m);
        float b1 = __shfl_xor(a1, m); int j1 = __shfl_xor(i1, m);
        bool c = better<true>(a0, i0, b0, j0);
        float r0 = c ? a0 : b0; int q0 = c ? i0 : j0;   // winner head
        float ws = c ? a1 : b1; int wi = c ? i1 : j1;   // winner's second
        float lh = c ? b0 : a0; int li = c ? j0 : i0;   // loser's head
        bool c2 = better<true>(ws, wi, lh, li);
        a0 = r0; i0 = q0;
        a1 = c2 ? ws : lh; i1 = c2 ? wi : li;
    }

    if (lane == 0) {
        outv[row * 2 + 0] = a0;        outv[row * 2 + 1] = a1;
        outi[row * 2 + 0] = (float)i0; outi[row * 2 + 1] = (float)i1;
    }
}

// ---------------------------------------------------------------------------
// Kernel 1: v_1 (8*16*64 = 8192 rows, 4096), top-4 smallest along last dim.
// One wave per row.
// ---------------------------------------------------------------------------
__global__ __launch_bounds__(256) void topk1_kernel(
    const float* __restrict__ x, float* __restrict__ outv, float* __restrict__ outi)
{
    const int wave = threadIdx.x >> 6;
    const int lane = threadIdx.x & 63;
    const int row  = blockIdx.x * 4 + wave;
    const float4* xr = (const float4*)(x + (size_t)row * 4096);

    float s0 = INFINITY, s1 = INFINITY, s2 = INFINITY, s3 = INFINITY;
    int   j0 = INT_MAX,  j1 = INT_MAX,  j2 = INT_MAX,  j3 = INT_MAX;

    for (int v = lane; v < 1024; v += 64) {
        float4 t = xr[v];
        int base = v * 4;
        ins4<false>(t.x, base,     s0, s1, s2, s3, j0, j1, j2, j3);
        ins4<false>(t.y, base + 1, s0, s1, s2, s3, j0, j1, j2, j3);
        ins4<false>(t.z, base + 2, s0, s1, s2, s3, j0, j1, j2, j3);
        ins4<false>(t.w, base + 3, s0, s1, s2, s3, j0, j1, j2, j3);
    }

    for (int m = 1; m < 64; m <<= 1) {
        float b0 = __shfl_xor(s0, m), b1 = __shfl_xor(s1, m);
        float b2 = __shfl_xor(s2, m), b3 = __shfl_xor(s3, m);
        int   q0 = __shfl_xor(j0, m), q1 = __shfl_xor(j1, m);
        int   q2 = __shfl_xor(j2, m), q3 = __shfl_xor(j3, m);
        merge4<false>(s0, s1, s2, s3, j0, j1, j2, j3, b0, b1, b2, b3, q0, q1, q2, q3);
    }

    if (lane == 0) {
        outv[row * 4 + 0] = s0; outv[row * 4 + 1] = s1;
        outv[row * 4 + 2] = s2; outv[row * 4 + 3] = s3;
        outi[row * 4 + 0] = (float)j0; outi[row * 4 + 1] = (float)j1;
        outi[row * 4 + 2] = (float)j2; outi[row * 4 + 3] = (float)j3;
    }
}

// ---------------------------------------------------------------------------
// Kernel 2 phase 1: v_2 (100000, 512), top-3 largest along dim 0 (columns).
// Each block handles a row-chunk over ALL 512 columns (2 cols per thread via
// float2 -> 2 KB contiguous per row per block). Writes per-block partial
// top-3 per column into workspace.
// ---------------------------------------------------------------------------
__global__ __launch_bounds__(256) void topk2_p1(
    const float* __restrict__ x, float* __restrict__ pval, int* __restrict__ pidx,
    int rpb)
{
    const int blk = blockIdx.x;
    const int t   = threadIdx.x;
    const int c0  = t * 2;
    int rbeg = blk * rpb;
    int rend = rbeg + rpb; if (rend > 100000) rend = 100000;

    float a0 = -INFINITY, a1 = -INFINITY, a2 = -INFINITY;
    int   ia0 = INT_MAX,  ia1 = INT_MAX,  ia2 = INT_MAX;
    float b0 = -INFINITY, b1 = -INFINITY, b2 = -INFINITY;
    int   ib0 = INT_MAX,  ib1 = INT_MAX,  ib2 = INT_MAX;

    for (int r = rbeg; r < rend; ++r) {
        float2 v = *(const float2*)(x + (size_t)r * 512 + c0);
        ins3<true>(v.x, r, a0, a1, a2, ia0, ia1, ia2);
        ins3<true>(v.y, r, b0, b1, b2, ib0, ib1, ib2);
    }

    size_t o = ((size_t)blk * 512 + c0) * 3;
    pval[o + 0] = a0; pval[o + 1] = a1; pval[o + 2] = a2;
    pidx[o + 0] = ia0; pidx[o + 1] = ia1; pidx[o + 2] = ia2;
    o += 3;
    pval[o + 0] = b0; pval[o + 1] = b1; pval[o + 2] = b2;
    pidx[o + 0] = ib0; pidx[o + 1] = ib1; pidx[o + 2] = ib2;
}

// Phase 2: merge nb partial top-3 lists per column. One wave per column.
__global__ __launch_bounds__(256) void topk2_p2(
    const float* __restrict__ pval, const int* __restrict__ pidx,
    float* __restrict__ outv, float* __restrict__ outi, int nb)
{
    const int wave = threadIdx.x >> 6;
    const int lane = threadIdx.x & 63;
    const int col  = blockIdx.x * 4 + wave;

    float s0 = -INFINITY, s1 = -INFINITY, s2 = -INFINITY, s3 = -INFINITY;
    int   j0 = INT_MAX,   j1 = INT_MAX,   j2 = INT_MAX,   j3 = INT_MAX;

    for (int p = lane; p < nb; p += 64) {
        size_t o = ((size_t)p * 512 + col) * 3;
        ins4<true>(pval[o + 0], pidx[o + 0], s0, s1, s2, s3, j0, j1, j2, j3);
        ins4<true>(pval[o + 1], pidx[o + 1], s0, s1, s2, s3, j0, j1, j2, j3);
        ins4<true>(pval[o + 2], pidx[o + 2], s0, s1, s2, s3, j0, j1, j2, j3);
    }

    for (int m = 1; m < 64; m <<= 1) {
        float b0 = __shfl_xor(s0, m), b1 = __shfl_xor(s1, m);
        float b2 = __shfl_xor(s2, m), b3 = __shfl_xor(s3, m);
        int   q0 = __shfl_xor(j0, m), q1 = __shfl_xor(j1, m);
        int   q2 = __shfl_xor(j2, m), q3 = __shfl_xor(j3, m);
        merge4<true>(s0, s1, s2, s3, j0, j1, j2, j3, b0, b1, b2, b3, q0, q1, q2, q3);
    }

    if (lane == 0) {
        // v_10 shape (3, 512): element (k, col) at k*512 + col
        outv[0 * 512 + col] = s0; outv[1 * 512 + col] = s1; outv[2 * 512 + col] = s2;
        outi[0 * 512 + col] = (float)j0; outi[1 * 512 + col] = (float)j1; outi[2 * 512 + col] = (float)j2;
    }
}

// Fallback (only if workspace is absurdly small): one block per column,
// strided reads, block-level reduce. Correct but slower.
__global__ __launch_bounds__(256) void topk2_direct(
    const float* __restrict__ x, float* __restrict__ outv, float* __restrict__ outi)
{
    const int col  = blockIdx.x;
    const int wave = threadIdx.x >> 6;
    const int lane = threadIdx.x & 63;

    float s0 = -INFINITY, s1 = -INFINITY, s2 = -INFINITY, s3 = -INFINITY;
    int   j0 = INT_MAX,   j1 = INT_MAX,   j2 = INT_MAX,   j3 = INT_MAX;

    for (int r = threadIdx.x; r < 100000; r += 256) {
        float v = x[(size_t)r * 512 + col];
        ins4<true>(v, r, s0, s1, s2, s3, j0, j1, j2, j3);
    }
    for (int m = 1; m < 64; m <<= 1) {
        float b0 = __shfl_xor(s0, m), b1 = __shfl_xor(s1, m);
        float b2 = __shfl_xor(s2, m), b3 = __shfl_xor(s3, m);
        int   q0 = __shfl_xor(j0, m), q1 = __shfl_xor(j1, m);
        int   q2 = __shfl_xor(j2, m), q3 = __shfl_xor(j3, m);
        merge4<true>(s0, s1, s2, s3, j0, j1, j2, j3, b0, b1, b2, b3, q0, q1, q2, q3);
    }
    __shared__ float sv[4][4];
    __shared__ int   si[4][4];
    if (lane == 0) {
        sv[wave][0] = s0; sv[wave][1] = s1; sv[wave][2] = s2; sv[wave][3] = s3;
        si[wave][0] = j0; si[wave][1] = j1; si[wave][2] = j2; si[wave][3] = j3;
    }
    __syncthreads();
    if (threadIdx.x == 0) {
        float r0 = sv[0][0], r1 = sv[0][1], r2 = sv[0][2], r3 = sv[0][3];
        int   k0 = si[0][0], k1 = si[0][1], k2 = si[0][2], k3 = si[0][3];
        for (int w = 1; w < 4; ++w) {
            merge4<true>(r0, r1, r2, r3, k0, k1, k2, k3,
                         sv[w][0], sv[w][1], sv[w][2], sv[w][3],
                         si[w][0], si[w][1], si[w][2], si[w][3]);
        }
        outv[0 * 512 + col] = r0; outv[1 * 512 + col] = r1; outv[2 * 512 + col] = r2;
        outi[0 * 512 + col] = (float)k0; outi[1 * 512 + col] = (float)k1; outi[2 * 512 + col] = (float)k2;
    }
}

extern "C" void kernel_launch(void* const* d_in, const int* in_sizes, int n_in,
                              void* d_out, int out_size, void* d_ws, size_t ws_size,
                              hipStream_t stream) {
    const float* v0 = (const float*)d_in[0];   // (4096, 32000)
    const float* v1 = (const float*)d_in[1];   // (8, 16, 64, 4096)
    const float* v2 = (const float*)d_in[2];   // (100000, 512)
    float* out = (float*)d_out;

    float* o_v4  = out;                 // (4096, 2) values
    float* o_v5  = out + 8192;          // (4096, 2) indices
    float* o_v7  = out + 16384;         // (8,16,64,4) values
    float* o_v8  = out + 49152;         // (8,16,64,4) indices
    float* o_v10 = out + 81920;         // (3, 512) values
    float* o_v11 = out + 83456;         // (3, 512) indices

    topk0_kernel<<<1024, 256, 0, stream>>>(v0, o_v4, o_v5);
    topk1_kernel<<<2048, 256, 0, stream>>>(v1, o_v7, o_v8);

    // TopK_2: adaptive two-phase via workspace (6.1 MB at nb=500).
    size_t per_block_bytes = 512ull * 3ull * 8ull;  // val + idx per block
    int nb = (int)(ws_size / per_block_bytes);
    if (nb > 500) nb = 500;
    if (nb >= 1) {
        int rpb = (100000 + nb - 1) / nb;
        float* pval = (float*)d_ws;
        int*   pidx = (int*)(pval + (size_t)nb * 512 * 3);
        topk2_p1<<<nb, 256, 0, stream>>>(v2, pval, pidx, rpb);
        topk2_p2<<<128, 256, 0, stream>>>(pval, pidx, o_v10, o_v11, nb);
    } else {
        topk2_direct<<<512, 256, 0, stream>>>(v2, o_v10, o_v11);
    }
}